// Round 5
// baseline (140.818 us; speedup 1.0000x reference)
//
#include <hip/hip_runtime.h>

// HDR+ align, 2-kernel, round 5.
// K1: pyramid via direct 36-tap conv per level, 3 barriers, 8 blocks/CU.
// K2: one block per S0 tile (4096 x 128thr), private quadtree chain L3->L0,
//     2 barriers/round, 8 blocks/CU for cross-block latency hiding.
// Constants: T=16, SR=4, PADD=1, SS=11, SSC=9, WIN=26, SW=0.1, GR=2, batch 4, 512x512.

#define NB 4
#define NPIX (NB * 512 * 512)

// Composite 1D tap: (normalized gaussian sigma=1 r=2) then avg-pool-2.
constexpr float H6[6] = {
    0.027244342f, 0.149345013f, 0.323410645f,
    0.323410645f, 0.149345013f, 0.027244342f
};

// ---------------------------------------------------------------------------
// K1: one block = 4x4 L3 region (32x32 L0). Grid (16,16,8), 256 thr.
// LDS: patch[60][64] 15.4KB + l1[28][28] 3.1KB + l2[12][12] 0.6KB = 19.1KB.
// Direct conv weight w(i,j) = H6[i]*H6[j] (compile-time constants).
// Per-level zero-pad handled by zeroing OOB entries of each LDS level array.
// ---------------------------------------------------------------------------
__global__ void __launch_bounds__(256, 8)
pyramid_kernel(const float* __restrict__ src, const float* __restrict__ dst,
               float* __restrict__ ws) {
    __shared__ float patch[60 * 64];
    __shared__ float l1[28 * 28];
    __shared__ float l2[12 * 12];

    float* sL1 = ws;
    float* dL1 = sL1 + 4 * 65536;
    float* sL2 = dL1 + 4 * 65536;
    float* dL2 = sL2 + 4 * 16384;
    float* sL3 = dL2 + 4 * 16384;
    float* dL3 = sL3 + 4 * 4096;

    const int bx = blockIdx.x, by = blockIdx.y, z = blockIdx.z;
    const int t = threadIdx.x;
    const float* in = (z < 4) ? (src + (size_t)z * 262144) : (dst + (size_t)(z - 4) * 262144);
    float* oL1 = ((z < 4) ? sL1 : dL1) + (size_t)(z & 3) * 65536;
    float* oL2 = ((z < 4) ? sL2 : dL2) + (size_t)(z & 3) * 16384;
    float* oL3 = ((z < 4) ? sL3 : dL3) + (size_t)(z & 3) * 4096;

    // P0: 60x60 L0 patch at (by*32-14, bx*32-14), zero OOB.
    {
        const int oy = by * 32 - 14, ox = bx * 32 - 14;
        for (int idx = t; idx < 3600; idx += 256) {
            int r = idx / 60, c = idx - r * 60;
            int gy = oy + r, gx = ox + c;
            float v = 0.f;
            if ((unsigned)gy < 512u && (unsigned)gx < 512u) v = in[gy * 512 + gx];
            patch[r * 64 + c] = v;
        }
    }
    __syncthreads();
    // P1: l1[28][28], direct 6x6; zero where L1 coord OOB.
    {
        const int oy = by * 16 - 6, ox = bx * 16 - 6;
        for (int idx = t; idx < 784; idx += 256) {
            int u = idx / 28, v = idx - u * 28;
            float a = 0.f;
            int y1 = oy + u, x1 = ox + v;
            if ((unsigned)y1 < 256u && (unsigned)x1 < 256u) {
                #pragma unroll
                for (int i = 0; i < 6; ++i) {
                    const float* p = &patch[(2 * u + i) * 64 + 2 * v];
                    #pragma unroll
                    for (int j = 0; j < 6; ++j) a = fmaf(H6[i] * H6[j], p[j], a);
                }
            }
            l1[u * 28 + v] = a;
        }
    }
    __syncthreads();
    // P2: write canonical L1 16x16; l2[12][12] direct; zero where L2 coord OOB.
    {
        int u = t >> 4, v = t & 15;
        oL1[(by * 16 + u) * 256 + bx * 16 + v] = l1[(6 + u) * 28 + 6 + v];
    }
    if (t < 144) {
        const int oy = by * 8 - 2, ox = bx * 8 - 2;
        int u = t / 12, v = t - u * 12;
        float a = 0.f;
        int y2 = oy + u, x2 = ox + v;
        if ((unsigned)y2 < 128u && (unsigned)x2 < 128u) {
            #pragma unroll
            for (int i = 0; i < 6; ++i) {
                const float* p = &l1[(2 * u + i) * 28 + 2 * v];
                #pragma unroll
                for (int j = 0; j < 6; ++j) a = fmaf(H6[i] * H6[j], p[j], a);
            }
        }
        l2[u * 12 + v] = a;
    }
    __syncthreads();
    // P3: write canonical L2 8x8; L3 4x4 direct -> global (L3 coords always in-bounds).
    if (t < 64) {
        int u = t >> 3, v = t & 7;
        oL2[(by * 8 + u) * 128 + bx * 8 + v] = l2[(2 + u) * 12 + 2 + v];
    } else if (t < 80) {
        int k = t - 64;
        int u = k >> 2, v = k & 3;
        float a = 0.f;
        #pragma unroll
        for (int i = 0; i < 6; ++i) {
            const float* p = &l2[(2 * u + i) * 12 + 2 * v];
            #pragma unroll
            for (int j = 0; j < 6; ++j) a = fmaf(H6[i] * H6[j], p[j], a);
        }
        oL3[(by * 4 + u) * 64 + bx * 4 + v] = a;
    }
}

// ---------------------------------------------------------------------------
// K2 helper: one level, 128 threads, 2 rows/lane SSD, 2 barriers.
// Result (roy,rox,rod) computed redundantly by every lane (identical fp ops on
// identical LDS data -> bitwise identical across lanes and waves).
// ---------------------------------------------------------------------------
__device__ __forceinline__ void do_level(const float* __restrict__ simg,
                                         const float* __restrict__ dimg, int H,
                                         int ty, int tx, float pary, float parx, bool first,
                                         float* win, float* st, float* dist, int lt,
                                         float& roy, float& rox, float& rod) {
    float dyf = 0.f, dxf = 0.f;
    if (!first) {
        float iy = (float)(ty * 16), ix = (float)(tx * 16);
        // _inherit: round(clip(2*par + i, 0, H-16) - i), half-to-even (rintf).
        dyf = rintf(fminf(fmaxf(2.f * pary + iy, 0.f), (float)(H - 16)) - iy);
        dxf = rintf(fminf(fmaxf(2.f * parx + ix, 0.f), (float)(H - 16)) - ix);
    }
    const int ioy = (int)dyf, iox = (int)dxf;
    const int y0 = ty * 16 + ioy - 5;
    const int x0 = tx * 16 + iox - 5;

    for (int idx = lt; idx < 676; idx += 128) {
        int r = idx / 26, c = idx - r * 26;
        int gy = min(max(y0 + r, 0), H - 1);
        int gx = min(max(x0 + c, 0), H - 1);
        win[r * 28 + c] = dimg[gy * H + gx];
    }
    if (lt < 64) {
        int r = lt >> 2, q = lt & 3;
        const float4* srow = (const float4*)(simg + (size_t)(ty * 16 + r) * H + tx * 16);
        ((float4*)&st[r * 16])[q] = srow[q];
    }
    __syncthreads();   // B1

    const int dy = lt >> 3;
    if (dy < 11) {
        float acc[11];
        #pragma unroll
        for (int q = 0; q < 11; ++q) acc[q] = 0.f;
        #pragma unroll
        for (int rr = 0; rr < 2; ++rr) {
            const int i = (lt & 7) * 2 + rr;
            float w[28], s[16];
            const float4* wp = (const float4*)&win[(dy + i) * 28];
            #pragma unroll
            for (int q = 0; q < 7; ++q) ((float4*)w)[q] = wp[q];
            const float4* sp = (const float4*)&st[i * 16];
            #pragma unroll
            for (int q = 0; q < 4; ++q) ((float4*)s)[q] = sp[q];
            #pragma unroll
            for (int dx = 0; dx < 11; ++dx) {
                #pragma unroll
                for (int j = 0; j < 16; ++j) {
                    float d = w[dx + j] - s[j];
                    acc[dx] = fmaf(d, d, acc[dx]);
                }
            }
        }
        #pragma unroll
        for (int m = 1; m <= 4; m <<= 1) {
            #pragma unroll
            for (int dx = 0; dx < 11; ++dx) acc[dx] += __shfl_xor(acc[dx], m);
        }
        if ((lt & 7) == 0) {
            float ay = (float)(dy - 5) * (1.f / 11.f);
            #pragma unroll
            for (int dx = 0; dx < 11; ++dx) {
                float ax = (float)(dx - 5) * (1.f / 11.f);
                dist[dy * 11 + dx] = acc[dx] * (1.f / 256.f) + 0.1f * (ay * ay + ax * ax);
            }
        }
    }
    __syncthreads();   // B2

    // Redundant per-lane argmin over central 9x9 (first occurrence on ties).
    const int l = lt & 63;
    float bv; int bk;
    {
        int k = l;
        int py = k / 9, px = k - (k / 9) * 9;
        bv = dist[(py + 1) * 11 + (px + 1)]; bk = k;
        k = l + 64;
        if (k < 81) {
            py = k / 9; px = k - (k / 9) * 9;
            float d = dist[(py + 1) * 11 + (px + 1)];
            if (d < bv) { bv = d; bk = k; }           // strict: tie keeps smaller k
        }
    }
    #pragma unroll
    for (int m = 1; m <= 32; m <<= 1) {
        float ov = __shfl_xor(bv, m);
        int   ok = __shfl_xor(bk, m);
        if (ov < bv || (ov == bv && ok < bk)) { bv = ov; bk = ok; }
    }
    // Redundant per-lane subpixel refine (broadcast LDS reads).
    {
        int py = bk / 9, px = bk - (bk / 9) * 9;
        float y00 = dist[(py + 0) * 11 + (px + 0)], y01 = dist[(py + 0) * 11 + (px + 1)], y02 = dist[(py + 0) * 11 + (px + 2)];
        float y10 = dist[(py + 1) * 11 + (px + 0)], y11 = dist[(py + 1) * 11 + (px + 1)], y12 = dist[(py + 1) * 11 + (px + 2)];
        float y20 = dist[(py + 2) * 11 + (px + 0)], y21 = dist[(py + 2) * 11 + (px + 1)], y22 = dist[(py + 2) * 11 + (px + 2)];

        float a11 = (y00 - 2.f * y01 + y02 + 2.f * y10 - 4.f * y11 + 2.f * y12 + y20 - 2.f * y21 + y22) * 0.25f;
        a11 = fmaxf(a11, 0.f);
        float a22 = (y00 + 2.f * y01 + y02 - 2.f * y10 - 4.f * y11 - 2.f * y12 + y20 + 2.f * y21 + y22) * 0.25f;
        a22 = fmaxf(a22, 0.f);
        float a12 = (y00 - y02 - y20 + y22) * 0.25f;
        float b1  = (-y00 + y02 - 2.f * y10 + 2.f * y12 - y20 + y22) * 0.125f;
        float b2  = (-y00 - 2.f * y01 - y02 + y20 + 2.f * y21 + y22) * 0.125f;

        float det  = a11 * a22 - a12 * a12;
        float a12z = (det < 0.f) ? 0.f : a12;
        float mu_x = -(a22 * b1 - a12z * b2) / det;   // inf/nan when det==0 -> filtered
        float mu_y = -(a11 * b2 - a12z * b1) / det;
        float mu_len = sqrtf(mu_x * mu_x + mu_y * mu_y);
        float addx = (mu_len < 1.f) ? mu_x : 0.f;     // NaN -> false, matches jnp.where
        float addy = (mu_len < 1.f) ? mu_y : 0.f;

        roy = dyf + (float)(py - 4) + addy;
        rox = dxf + (float)(px - 4) + addx;
        rod = bv;
    }
}

// ---------------------------------------------------------------------------
// K2: one block per S0 tile (4096 blocks, 128 thr). Private chain L3->L2->L1->L0
// (each block redundantly computes its ancestors), then fused pixel expand.
// ---------------------------------------------------------------------------
__global__ void __launch_bounds__(128, 4)
step_chain_kernel(const float* __restrict__ src, const float* __restrict__ dst,
                  const float* __restrict__ ws, float* __restrict__ out) {
    __shared__ float win[26 * 28];
    __shared__ float st[256];
    __shared__ float dist[128];

    const float* sL1 = ws;
    const float* dL1 = sL1 + 4 * 65536;
    const float* sL2 = dL1 + 4 * 65536;
    const float* dL2 = sL2 + 4 * 16384;
    const float* sL3 = dL2 + 4 * 16384;
    const float* dL3 = sL3 + 4 * 4096;

    const int gid = blockIdx.x;            // 0..4095
    const int b   = gid >> 10;
    const int ty0 = (gid >> 5) & 31;
    const int tx0 = gid & 31;
    const int lt  = threadIdx.x;

    const float* s0 = src + (size_t)b * 262144; const float* d0 = dst + (size_t)b * 262144;
    const float* s1 = sL1 + (size_t)b * 65536;  const float* d1 = dL1 + (size_t)b * 65536;
    const float* s2 = sL2 + (size_t)b * 16384;  const float* d2 = dL2 + (size_t)b * 16384;
    const float* s3 = sL3 + (size_t)b * 4096;   const float* d3 = dL3 + (size_t)b * 4096;

    float oy, ox, od;
    do_level(s3, d3,  64, ty0 >> 3, tx0 >> 3, 0.f, 0.f, true,  win, st, dist, lt, oy, ox, od);
    do_level(s2, d2, 128, ty0 >> 2, tx0 >> 2, oy, ox, false, win, st, dist, lt, oy, ox, od);
    do_level(s1, d1, 256, ty0 >> 1, tx0 >> 1, oy, ox, false, win, st, dist, lt, oy, ox, od);
    do_level(s0, d0, 512, ty0,      tx0,      oy, ox, false, win, st, dist, lt, oy, ox, od);

    // Fused expand: every lane holds identical (oy,ox,od); 2 pixels/lane.
    int r = lt >> 3, c = (lt & 7) * 2;
    int pyy = ty0 * 16 + r, pxx = tx0 * 16 + c;
    size_t pi = ((size_t)(b * 512 + pyy)) * 512 + pxx;
    float2 o; o.x = oy; o.y = ox;
    ((float2*)out)[pi]     = o;
    ((float2*)out)[pi + 1] = o;
    float2 dd; dd.x = od; dd.y = od;
    *(float2*)(out + (size_t)NPIX * 2 + pi) = dd;
}

extern "C" void kernel_launch(void* const* d_in, const int* in_sizes, int n_in,
                              void* d_out, int out_size, void* d_ws, size_t ws_size,
                              hipStream_t stream) {
    const float* src = (const float*)d_in[0];   // (4,1,512,512)
    const float* dst = (const float*)d_in[1];   // (4,1,512,512)
    float* out = (float*)d_out;                  // offsets (NPIX*2) ++ dist (NPIX)
    float* ws  = (float*)d_ws;                   // pyramid levels, 2.75 MB

    hipLaunchKernelGGL(pyramid_kernel, dim3(16, 16, 8), dim3(256), 0, stream, src, dst, ws);
    hipLaunchKernelGGL(step_chain_kernel, dim3(4096), dim3(128), 0, stream, src, dst, ws, out);
}

// Round 6
// 126.516 us; speedup vs baseline: 1.1130x; 1.1130x over previous
//
#include <hip/hip_runtime.h>

// HDR+ align, 2-kernel, round 6.
// K1: pyramid, 2x2-L3 tiles (13.8KB LDS, 8192 blocks, 8/CU), separable conv.
// K2: 1024 blocks x 256thr; L3/L2/L1 full-width rounds, then ONE quad round
//     where each of the 4 waves owns one S0 child (no slot serialization).
// Constants: T=16, SR=4, PADD=1, SS=11, SSC=9, WIN=26, SW=0.1, GR=2, batch 4, 512x512.

#define NB 4
#define NPIX (NB * 512 * 512)

// Composite 1D tap: (normalized gaussian sigma=1 r=2) then avg-pool-2.
constexpr float H6[6] = {
    0.027244342f, 0.149345013f, 0.323410645f,
    0.323410645f, 0.149345013f, 0.027244342f
};

// ---------------------------------------------------------------------------
// K1: one block = 2x2 L3 region (16x16 L0 region). Grid (32,32,8), 256 thr.
// Mapping (level k+1 from level k): out[Y,X] = sum_{i,j} H6[i]H6[j] Lk[2Y-2+i, 2X-2+j],
// with Lk zero outside its bounds (per-level zero-pad of the reference conv).
// LDS: patch[44][44] + tmpH1[44][20] + l1[20][20] + tmpH2[20][8] + l2[8][8]
//      + tmpH3[8][2] = 13.8 KB -> 8 blocks/CU (wave-limited).
// ---------------------------------------------------------------------------
__global__ void __launch_bounds__(256, 8)
pyramid_kernel(const float* __restrict__ src, const float* __restrict__ dst,
               float* __restrict__ ws) {
    __shared__ float patch[44 * 44];
    __shared__ float tmpH1[44 * 20];
    __shared__ float l1[20 * 20];
    __shared__ float tmpH2[20 * 8];
    __shared__ float l2[8 * 8];
    __shared__ float tmpH3[8 * 2];

    float* sL1 = ws;
    float* dL1 = sL1 + 4 * 65536;
    float* sL2 = dL1 + 4 * 65536;
    float* dL2 = sL2 + 4 * 16384;
    float* sL3 = dL2 + 4 * 16384;
    float* dL3 = sL3 + 4 * 4096;

    const int bx = blockIdx.x, by = blockIdx.y, z = blockIdx.z;
    const int t = threadIdx.x;
    const float* in = (z < 4) ? (src + (size_t)z * 262144) : (dst + (size_t)(z - 4) * 262144);
    float* oL1 = ((z < 4) ? sL1 : dL1) + (size_t)(z & 3) * 65536;
    float* oL2 = ((z < 4) ? sL2 : dL2) + (size_t)(z & 3) * 16384;
    float* oL3 = ((z < 4) ? sL3 : dL3) + (size_t)(z & 3) * 4096;

    // P0: 44x44 L0 patch at (by*16-14, bx*16-14), zero OOB.
    {
        const int oy = by * 16 - 14, ox = bx * 16 - 14;
        for (int idx = t; idx < 1936; idx += 256) {
            int r = idx / 44, c = idx - r * 44;
            int gy = oy + r, gx = ox + c;
            float v = 0.f;
            if ((unsigned)gy < 512u && (unsigned)gx < 512u) v = in[gy * 512 + gx];
            patch[r * 44 + c] = v;
        }
    }
    __syncthreads();
    // P1: horizontal -> tmpH1[44][20]
    for (int idx = t; idx < 880; idx += 256) {
        int r = idx / 20, v = idx - r * 20;
        const float* p = &patch[r * 44 + 2 * v];
        float a = 0.f;
        #pragma unroll
        for (int j = 0; j < 6; ++j) a = fmaf(H6[j], p[j], a);
        tmpH1[r * 20 + v] = a;
    }
    __syncthreads();
    // P2: vertical -> l1[20][20]; zero where L1 coord (by*8-6+u, bx*8-6+v) OOB.
    {
        const int oy = by * 8 - 6, ox = bx * 8 - 6;
        for (int idx = t; idx < 400; idx += 256) {
            int u = idx / 20, v = idx - u * 20;
            float a = 0.f;
            if ((unsigned)(oy + u) < 256u && (unsigned)(ox + v) < 256u) {
                #pragma unroll
                for (int i = 0; i < 6; ++i) a = fmaf(H6[i], tmpH1[(2 * u + i) * 20 + v], a);
            }
            l1[u * 20 + v] = a;
        }
    }
    __syncthreads();
    // P3: write canonical L1 8x8 + horizontal -> tmpH2[20][8]
    if (t < 64) {
        int u = t >> 3, v = t & 7;
        oL1[(by * 8 + u) * 256 + bx * 8 + v] = l1[(6 + u) * 20 + 6 + v];
    }
    if (t < 160) {
        int r = t >> 3, v = t & 7;
        const float* p = &l1[r * 20 + 2 * v];
        float a = 0.f;
        #pragma unroll
        for (int j = 0; j < 6; ++j) a = fmaf(H6[j], p[j], a);
        tmpH2[r * 8 + v] = a;
    }
    __syncthreads();
    // P4: vertical -> l2[8][8]; zero where L2 coord (by*4-2+u, bx*4-2+v) OOB.
    if (t < 64) {
        const int oy = by * 4 - 2, ox = bx * 4 - 2;
        int u = t >> 3, v = t & 7;
        float a = 0.f;
        if ((unsigned)(oy + u) < 128u && (unsigned)(ox + v) < 128u) {
            #pragma unroll
            for (int i = 0; i < 6; ++i) a = fmaf(H6[i], tmpH2[(2 * u + i) * 8 + v], a);
        }
        l2[u * 8 + v] = a;
    }
    __syncthreads();
    // P5: write canonical L2 4x4 + horizontal -> tmpH3[8][2]
    if (t < 16) {
        int u = t >> 2, v = t & 3;
        oL2[(by * 4 + u) * 128 + bx * 4 + v] = l2[(2 + u) * 8 + 2 + v];
    } else if (t >= 64 && t < 80) {
        int k = t - 64;
        int r = k >> 1, v = k & 1;
        const float* p = &l2[r * 8 + 2 * v];
        float a = 0.f;
        #pragma unroll
        for (int j = 0; j < 6; ++j) a = fmaf(H6[j], p[j], a);
        tmpH3[r * 2 + v] = a;
    }
    __syncthreads();
    // P6: vertical -> L3 2x2 (always in-bounds), write global.
    if (t < 4) {
        int u = t >> 1, v = t & 1;
        float a = 0.f;
        #pragma unroll
        for (int i = 0; i < 6; ++i) a = fmaf(H6[i], tmpH3[(2 * u + i) * 2 + v], a);
        oL3[(by * 2 + u) * 64 + bx * 2 + v] = a;
    }
}

// ---------------------------------------------------------------------------
// Shared subpixel refine + offset compose (identical fp ops on identical LDS
// data -> bitwise identical across all executing lanes).
// ---------------------------------------------------------------------------
__device__ __forceinline__ void refine(const float* dist, int bk, float dyf, float dxf,
                                       float& roy, float& rox) {
    int py = bk / 9, px = bk - (bk / 9) * 9;
    float y00 = dist[(py + 0) * 11 + (px + 0)], y01 = dist[(py + 0) * 11 + (px + 1)], y02 = dist[(py + 0) * 11 + (px + 2)];
    float y10 = dist[(py + 1) * 11 + (px + 0)], y11 = dist[(py + 1) * 11 + (px + 1)], y12 = dist[(py + 1) * 11 + (px + 2)];
    float y20 = dist[(py + 2) * 11 + (px + 0)], y21 = dist[(py + 2) * 11 + (px + 1)], y22 = dist[(py + 2) * 11 + (px + 2)];

    float a11 = (y00 - 2.f * y01 + y02 + 2.f * y10 - 4.f * y11 + 2.f * y12 + y20 - 2.f * y21 + y22) * 0.25f;
    a11 = fmaxf(a11, 0.f);
    float a22 = (y00 + 2.f * y01 + y02 - 2.f * y10 - 4.f * y11 - 2.f * y12 + y20 + 2.f * y21 + y22) * 0.25f;
    a22 = fmaxf(a22, 0.f);
    float a12 = (y00 - y02 - y20 + y22) * 0.25f;
    float b1  = (-y00 + y02 - 2.f * y10 + 2.f * y12 - y20 + y22) * 0.125f;
    float b2  = (-y00 - 2.f * y01 - y02 + y20 + 2.f * y21 + y22) * 0.125f;

    float det  = a11 * a22 - a12 * a12;
    float a12z = (det < 0.f) ? 0.f : a12;
    float mu_x = -(a22 * b1 - a12z * b2) / det;   // inf/nan when det==0 -> filtered
    float mu_y = -(a11 * b2 - a12z * b1) / det;
    float mu_len = sqrtf(mu_x * mu_x + mu_y * mu_y);
    float addx = (mu_len < 1.f) ? mu_x : 0.f;     // NaN -> false, matches jnp.where
    float addy = (mu_len < 1.f) ? mu_y : 0.f;

    roy = dyf + (float)(py - 4) + addy;
    rox = dxf + (float)(px - 4) + addx;
}

__device__ __forceinline__ void inherit(int H, int ty, int tx, float pary, float parx,
                                        float& dyf, float& dxf) {
    float iy = (float)(ty * 16), ix = (float)(tx * 16);
    // _inherit: round(clip(2*par + i, 0, H-16) - i), half-to-even (rintf).
    dyf = rintf(fminf(fmaxf(2.f * pary + iy, 0.f), (float)(H - 16)) - iy);
    dxf = rintf(fminf(fmaxf(2.f * parx + ix, 0.f), (float)(H - 16)) - ix);
}

// One full-width (256-thread) block-matching level; 2 barriers.
__device__ __forceinline__ void full_level(const float* __restrict__ simg,
                                           const float* __restrict__ dimg, int H,
                                           int ty, int tx, float pary, float parx, bool first,
                                           float* win, float* st, float* dist, int t,
                                           float& roy, float& rox) {
    float dyf = 0.f, dxf = 0.f;
    if (!first) inherit(H, ty, tx, pary, parx, dyf, dxf);
    const int ioy = (int)dyf, iox = (int)dxf;
    const int y0 = ty * 16 + ioy - 5;
    const int x0 = tx * 16 + iox - 5;

    for (int idx = t; idx < 676; idx += 256) {
        int r = idx / 26, c = idx - r * 26;
        int gy = min(max(y0 + r, 0), H - 1);
        int gx = min(max(x0 + c, 0), H - 1);
        win[r * 28 + c] = dimg[gy * H + gx];
    }
    if (t < 64) {
        int r = t >> 2, q = t & 3;
        const float4* srow = (const float4*)(simg + (size_t)(ty * 16 + r) * H + tx * 16);
        ((float4*)&st[r * 16])[q] = srow[q];
    }
    __syncthreads();   // B1

    const int dy = t >> 4;
    if (dy < 11) {
        float acc[11];
        #pragma unroll
        for (int q = 0; q < 11; ++q) acc[q] = 0.f;
        const int i = t & 15;
        float w[28], s[16];
        const float4* wp = (const float4*)&win[(dy + i) * 28];
        #pragma unroll
        for (int q = 0; q < 7; ++q) ((float4*)w)[q] = wp[q];
        const float4* sp = (const float4*)&st[i * 16];
        #pragma unroll
        for (int q = 0; q < 4; ++q) ((float4*)s)[q] = sp[q];
        #pragma unroll
        for (int dx = 0; dx < 11; ++dx) {
            #pragma unroll
            for (int j = 0; j < 16; ++j) {
                float d = w[dx + j] - s[j];
                acc[dx] = fmaf(d, d, acc[dx]);
            }
        }
        #pragma unroll
        for (int m = 1; m <= 8; m <<= 1) {
            #pragma unroll
            for (int dx = 0; dx < 11; ++dx) acc[dx] += __shfl_xor(acc[dx], m);
        }
        if ((t & 15) == 0) {
            float ay = (float)(dy - 5) * (1.f / 11.f);
            #pragma unroll
            for (int dx = 0; dx < 11; ++dx) {
                float ax = (float)(dx - 5) * (1.f / 11.f);
                dist[dy * 11 + dx] = acc[dx] * (1.f / 256.f) + 0.1f * (ay * ay + ax * ax);
            }
        }
    }
    __syncthreads();   // B2

    // Redundant per-lane argmin over central 9x9 (first occurrence on ties).
    const int l = t & 63;
    float bv; int bk;
    {
        int k = l;
        int py = k / 9, px = k - (k / 9) * 9;
        bv = dist[(py + 1) * 11 + (px + 1)]; bk = k;
        k = l + 64;
        if (k < 81) {
            py = k / 9; px = k - (k / 9) * 9;
            float d = dist[(py + 1) * 11 + (px + 1)];
            if (d < bv) { bv = d; bk = k; }           // strict: tie keeps smaller k
        }
    }
    #pragma unroll
    for (int m = 1; m <= 32; m <<= 1) {
        float ov = __shfl_xor(bv, m);
        int   ok = __shfl_xor(bk, m);
        if (ov < bv || (ov == bv && ok < bk)) { bv = ov; bk = ok; }
    }
    refine(dist, bk, dyf, dxf, roy, rox);
}

// ---------------------------------------------------------------------------
// K2: one block per S1 tile (1024 blocks, 256 thr, 4/CU). Rounds L3,L2,L1
// full-width; then ONE quad round: wave w handles S0 child (2*ty1+(w>>1),
// 2*tx1+(w&1)) with its own LDS buffers; fused pixel expand (4 px/lane).
// ---------------------------------------------------------------------------
__global__ void __launch_bounds__(256, 4)
step_chain_kernel(const float* __restrict__ src, const float* __restrict__ dst,
                  const float* __restrict__ ws, float* __restrict__ out) {
    __shared__ float winC[4][26 * 28];
    __shared__ float stC[4][256];
    __shared__ float distC[4][128];

    const float* sL1 = ws;
    const float* dL1 = sL1 + 4 * 65536;
    const float* sL2 = dL1 + 4 * 65536;
    const float* dL2 = sL2 + 4 * 16384;
    const float* sL3 = dL2 + 4 * 16384;
    const float* dL3 = sL3 + 4 * 4096;

    const int gid = blockIdx.x;
    const int b   = gid >> 8;
    const int ty1 = (gid >> 4) & 15;
    const int tx1 = gid & 15;
    const int t   = threadIdx.x;

    const float* s0 = src + (size_t)b * 262144; const float* d0 = dst + (size_t)b * 262144;
    const float* s1 = sL1 + (size_t)b * 65536;  const float* d1 = dL1 + (size_t)b * 65536;
    const float* s2 = sL2 + (size_t)b * 16384;  const float* d2 = dL2 + (size_t)b * 16384;
    const float* s3 = sL3 + (size_t)b * 4096;   const float* d3 = dL3 + (size_t)b * 4096;

    float oy, ox;
    full_level(s3, d3,  64, ty1 >> 2, tx1 >> 2, 0.f, 0.f, true,
               winC[0], stC[0], distC[0], t, oy, ox);
    full_level(s2, d2, 128, ty1 >> 1, tx1 >> 1, oy, ox, false,
               winC[0], stC[0], distC[0], t, oy, ox);
    full_level(s1, d1, 256, ty1,      tx1,      oy, ox, false,
               winC[0], stC[0], distC[0], t, oy, ox);

    // ---- quad round: wave w owns one S0 child ----
    const int w    = t >> 6;
    const int lane = t & 63;
    const int ty0  = 2 * ty1 + (w >> 1);
    const int tx0  = 2 * tx1 + (w & 1);
    float* win  = winC[w];
    float* st   = stC[w];
    float* dist = distC[w];

    float dyf, dxf;
    inherit(512, ty0, tx0, oy, ox, dyf, dxf);
    const int ioy = (int)dyf, iox = (int)dxf;
    const int y0 = ty0 * 16 + ioy - 5;
    const int x0 = tx0 * 16 + iox - 5;

    for (int idx = lane; idx < 676; idx += 64) {
        int r = idx / 26, c = idx - r * 26;
        int gy = min(max(y0 + r, 0), 511);
        int gx = min(max(x0 + c, 0), 511);
        win[r * 28 + c] = d0[gy * 512 + gx];
    }
    {
        int r = lane >> 2, q = lane & 3;
        const float4* srow = (const float4*)(s0 + (size_t)(ty0 * 16 + r) * 512 + tx0 * 16);
        ((float4*)&st[r * 16])[q] = srow[q];
    }
    __syncthreads();   // all 4 waves' data staged

    {
        const int dy = lane >> 2;
        if (dy < 11) {
            float acc[11];
            #pragma unroll
            for (int q = 0; q < 11; ++q) acc[q] = 0.f;
            #pragma unroll
            for (int rr = 0; rr < 4; ++rr) {
                const int i = (lane & 3) * 4 + rr;
                float wv[28], s[16];
                const float4* wp = (const float4*)&win[(dy + i) * 28];
                #pragma unroll
                for (int q = 0; q < 7; ++q) ((float4*)wv)[q] = wp[q];
                const float4* sp = (const float4*)&st[i * 16];
                #pragma unroll
                for (int q = 0; q < 4; ++q) ((float4*)s)[q] = sp[q];
                #pragma unroll
                for (int dx = 0; dx < 11; ++dx) {
                    #pragma unroll
                    for (int j = 0; j < 16; ++j) {
                        float d = wv[dx + j] - s[j];
                        acc[dx] = fmaf(d, d, acc[dx]);
                    }
                }
            }
            #pragma unroll
            for (int m = 1; m <= 2; m <<= 1) {
                #pragma unroll
                for (int dx = 0; dx < 11; ++dx) acc[dx] += __shfl_xor(acc[dx], m);
            }
            if ((lane & 3) == 0) {
                float ay = (float)(dy - 5) * (1.f / 11.f);
                #pragma unroll
                for (int dx = 0; dx < 11; ++dx) {
                    float ax = (float)(dx - 5) * (1.f / 11.f);
                    dist[dy * 11 + dx] = acc[dx] * (1.f / 256.f) + 0.1f * (ay * ay + ax * ax);
                }
            }
        }
    }
    __syncthreads();   // all 4 dists complete

    // Per-wave redundant argmin (first occurrence on ties) + refine.
    float bv; int bk;
    {
        int k = lane;
        int py = k / 9, px = k - (k / 9) * 9;
        bv = dist[(py + 1) * 11 + (px + 1)]; bk = k;
        k = lane + 64;
        if (k < 81) {
            py = k / 9; px = k - (k / 9) * 9;
            float d = dist[(py + 1) * 11 + (px + 1)];
            if (d < bv) { bv = d; bk = k; }
        }
    }
    #pragma unroll
    for (int m = 1; m <= 32; m <<= 1) {
        float ov = __shfl_xor(bv, m);
        int   ok = __shfl_xor(bk, m);
        if (ov < bv || (ov == bv && ok < bk)) { bv = ov; bk = ok; }
    }
    float coy, cox;
    refine(dist, bk, dyf, dxf, coy, cox);
    const float od = bv;

    // Fused expand: 4 px/lane (row = lane>>2, cols (lane&3)*4 .. +3).
    {
        int r = lane >> 2, c = (lane & 3) * 4;
        int pyy = ty0 * 16 + r, pxx = tx0 * 16 + c;
        size_t pi = ((size_t)(b * 512 + pyy)) * 512 + pxx;
        float4 o2; o2.x = coy; o2.y = cox; o2.z = coy; o2.w = cox;
        float4* po = (float4*)(out + 2 * pi);
        po[0] = o2; po[1] = o2;
        float4 dd; dd.x = od; dd.y = od; dd.z = od; dd.w = od;
        *(float4*)(out + (size_t)NPIX * 2 + pi) = dd;
    }
}

extern "C" void kernel_launch(void* const* d_in, const int* in_sizes, int n_in,
                              void* d_out, int out_size, void* d_ws, size_t ws_size,
                              hipStream_t stream) {
    const float* src = (const float*)d_in[0];   // (4,1,512,512)
    const float* dst = (const float*)d_in[1];   // (4,1,512,512)
    float* out = (float*)d_out;                  // offsets (NPIX*2) ++ dist (NPIX)
    float* ws  = (float*)d_ws;                   // pyramid levels, 2.75 MB

    hipLaunchKernelGGL(pyramid_kernel, dim3(32, 32, 8), dim3(256), 0, stream, src, dst, ws);
    hipLaunchKernelGGL(step_chain_kernel, dim3(1024), dim3(256), 0, stream, src, dst, ws, out);
}

// Round 7
// 112.377 us; speedup vs baseline: 1.2531x; 1.1258x over previous
//
#include <hip/hip_runtime.h>

// HDR+ align, 2-kernel, round 7. Base = R4 (best: 112.1us) with L0 restructured:
// when no inherit-clamp triggers (uniform per block, ~77% of tiles), the four S0
// children share one integer offset -> merged 42x42 window + 32x32 src staged
// once, one SSD phase, per-wave argmin (barriers 10 -> 8, one staging latency
// chain instead of two). Border blocks use R4's exact two half-round fallback.
// Constants: T=16, SR=4, PADD=1, SS=11, SSC=9, WIN=26, SW=0.1, GR=2, batch 4, 512x512.

#define NB 4
#define NPIX (NB * 512 * 512)

// Composite 1D tap: (normalized gaussian sigma=1 r=2) then avg-pool-2.
constexpr float H6[6] = {
    0.027244342f, 0.149345013f, 0.323410645f,
    0.323410645f, 0.149345013f, 0.027244342f
};

// ---------------------------------------------------------------------------
// K1 (identical to R4): one block = 4x4 L3 region. Grid (16,16,8), 256 thr.
// ---------------------------------------------------------------------------
__global__ void __launch_bounds__(256, 4)
pyramid_kernel(const float* __restrict__ src, const float* __restrict__ dst,
               float* __restrict__ ws) {
    __shared__ float smem[5520];
    float* patch = smem;            // 60 rows, stride 64
    float* tmpH1 = smem + 3840;     // 60 rows, stride 28
    float* l1    = smem;            // 28 rows, stride 28 (overlays dead patch)
    float* tmpH2 = smem + 784;      // 28 rows, stride 12
    float* l2    = smem + 1120;     // 12 rows, stride 12
    float* tmpH3 = smem + 1264;     // 12 rows, stride 4

    float* sL1 = ws;
    float* dL1 = sL1 + 4 * 65536;
    float* sL2 = dL1 + 4 * 65536;
    float* dL2 = sL2 + 4 * 16384;
    float* sL3 = dL2 + 4 * 16384;
    float* dL3 = sL3 + 4 * 4096;

    const int bx = blockIdx.x, by = blockIdx.y, z = blockIdx.z;
    const int t = threadIdx.x;
    const float* in = (z < 4) ? (src + (size_t)z * 262144) : (dst + (size_t)(z - 4) * 262144);
    float* oL1 = ((z < 4) ? sL1 : dL1) + (size_t)(z & 3) * 65536;
    float* oL2 = ((z < 4) ? sL2 : dL2) + (size_t)(z & 3) * 16384;
    float* oL3 = ((z < 4) ? sL3 : dL3) + (size_t)(z & 3) * 4096;

    {
        const int oy = by * 32 - 14, ox = bx * 32 - 14;
        for (int idx = t; idx < 3600; idx += 256) {
            int r = idx / 60, c = idx - r * 60;
            int gy = oy + r, gx = ox + c;
            float v = 0.f;
            if ((unsigned)gy < 512u && (unsigned)gx < 512u) v = in[gy * 512 + gx];
            patch[r * 64 + c] = v;
        }
    }
    __syncthreads();
    for (int idx = t; idx < 1680; idx += 256) {
        int r = idx / 28, v = idx - r * 28;
        const float* p = &patch[r * 64 + 2 * v];
        float a = 0.f;
        #pragma unroll
        for (int bq = 0; bq < 6; ++bq) a = fmaf(H6[bq], p[bq], a);
        tmpH1[r * 28 + v] = a;
    }
    __syncthreads();
    {
        const int oy = by * 16 - 6, ox = bx * 16 - 6;
        for (int idx = t; idx < 784; idx += 256) {
            int u = idx / 28, v = idx - u * 28;
            float a = 0.f;
            int y1 = oy + u, x1 = ox + v;
            if ((unsigned)y1 < 256u && (unsigned)x1 < 256u) {
                #pragma unroll
                for (int bq = 0; bq < 6; ++bq) a = fmaf(H6[bq], tmpH1[(2 * u + bq) * 28 + v], a);
            }
            l1[u * 28 + v] = a;
        }
    }
    __syncthreads();
    {
        int u = t >> 4, v = t & 15;
        oL1[(by * 16 + u) * 256 + bx * 16 + v] = l1[(6 + u) * 28 + 6 + v];
    }
    for (int idx = t; idx < 336; idx += 256) {
        int r = idx / 12, v = idx - r * 12;
        const float* p = &l1[r * 28 + 2 * v];
        float a = 0.f;
        #pragma unroll
        for (int bq = 0; bq < 6; ++bq) a = fmaf(H6[bq], p[bq], a);
        tmpH2[r * 12 + v] = a;
    }
    __syncthreads();
    {
        const int oy = by * 8 - 2, ox = bx * 8 - 2;
        if (t < 144) {
            int u = t / 12, v = t - u * 12;
            float a = 0.f;
            int y2 = oy + u, x2 = ox + v;
            if ((unsigned)y2 < 128u && (unsigned)x2 < 128u) {
                #pragma unroll
                for (int bq = 0; bq < 6; ++bq) a = fmaf(H6[bq], tmpH2[(2 * u + bq) * 12 + v], a);
            }
            l2[u * 12 + v] = a;
        }
    }
    __syncthreads();
    if (t < 64) {
        int u = t >> 3, v = t & 7;
        oL2[(by * 8 + u) * 128 + bx * 8 + v] = l2[(2 + u) * 12 + 2 + v];
    } else if (t < 112) {
        int idx = t - 64;
        int r = idx >> 2, v = idx & 3;
        const float* p = &l2[r * 12 + 2 * v];
        float a = 0.f;
        #pragma unroll
        for (int bq = 0; bq < 6; ++bq) a = fmaf(H6[bq], p[bq], a);
        tmpH3[r * 4 + v] = a;
    }
    __syncthreads();
    if (t < 16) {
        int u = t >> 2, v = t & 3;
        float a = 0.f;
        #pragma unroll
        for (int bq = 0; bq < 6; ++bq) a = fmaf(H6[bq], tmpH3[(2 * u + bq) * 4 + v], a);
        oL3[(by * 4 + u) * 64 + bx * 4 + v] = a;
    }
}

// ---------------------------------------------------------------------------
// Shared helpers (identical math to R4; redundant per-lane -> bitwise identical).
// ---------------------------------------------------------------------------
__device__ __forceinline__ void refine(const float* dist, int bk, float dyf, float dxf,
                                       float& roy, float& rox) {
    int py = bk / 9, px = bk - (bk / 9) * 9;
    float y00 = dist[(py + 0) * 11 + (px + 0)], y01 = dist[(py + 0) * 11 + (px + 1)], y02 = dist[(py + 0) * 11 + (px + 2)];
    float y10 = dist[(py + 1) * 11 + (px + 0)], y11 = dist[(py + 1) * 11 + (px + 1)], y12 = dist[(py + 1) * 11 + (px + 2)];
    float y20 = dist[(py + 2) * 11 + (px + 0)], y21 = dist[(py + 2) * 11 + (px + 1)], y22 = dist[(py + 2) * 11 + (px + 2)];

    float a11 = (y00 - 2.f * y01 + y02 + 2.f * y10 - 4.f * y11 + 2.f * y12 + y20 - 2.f * y21 + y22) * 0.25f;
    a11 = fmaxf(a11, 0.f);
    float a22 = (y00 + 2.f * y01 + y02 - 2.f * y10 - 4.f * y11 - 2.f * y12 + y20 + 2.f * y21 + y22) * 0.25f;
    a22 = fmaxf(a22, 0.f);
    float a12 = (y00 - y02 - y20 + y22) * 0.25f;
    float b1  = (-y00 + y02 - 2.f * y10 + 2.f * y12 - y20 + y22) * 0.125f;
    float b2  = (-y00 - 2.f * y01 - y02 + y20 + 2.f * y21 + y22) * 0.125f;

    float det  = a11 * a22 - a12 * a12;
    float a12z = (det < 0.f) ? 0.f : a12;
    float mu_x = -(a22 * b1 - a12z * b2) / det;   // inf/nan when det==0 -> filtered
    float mu_y = -(a11 * b2 - a12z * b1) / det;
    float mu_len = sqrtf(mu_x * mu_x + mu_y * mu_y);
    float addx = (mu_len < 1.f) ? mu_x : 0.f;     // NaN -> false, matches jnp.where
    float addy = (mu_len < 1.f) ? mu_y : 0.f;

    roy = dyf + (float)(py - 4) + addy;
    rox = dxf + (float)(px - 4) + addx;
}

__device__ __forceinline__ void inherit(int H, int ty, int tx, float pary, float parx,
                                        float& dyf, float& dxf) {
    float iy = (float)(ty * 16), ix = (float)(tx * 16);
    // _inherit: round(clip(2*par + i, 0, H-16) - i), half-to-even (rintf).
    dyf = rintf(fminf(fmaxf(2.f * pary + iy, 0.f), (float)(H - 16)) - iy);
    dxf = rintf(fminf(fmaxf(2.f * parx + ix, 0.f), (float)(H - 16)) - ix);
}

__device__ __forceinline__ void argmin81(const float* dist, int lane, float& bv, int& bk) {
    {
        int k = lane;
        int py = k / 9, px = k - (k / 9) * 9;
        bv = dist[(py + 1) * 11 + (px + 1)]; bk = k;
        k = lane + 64;
        if (k < 81) {
            py = k / 9; px = k - (k / 9) * 9;
            float d = dist[(py + 1) * 11 + (px + 1)];
            if (d < bv) { bv = d; bk = k; }           // strict: tie keeps smaller k
        }
    }
    #pragma unroll
    for (int m = 1; m <= 32; m <<= 1) {
        float ov = __shfl_xor(bv, m);
        int   ok = __shfl_xor(bk, m);
        if (ov < bv || (ov == bv && ok < bk)) { bv = ov; bk = ok; }
    }
}

// Full-width (256-thread) level, 2 barriers — R4's full_level verbatim.
__device__ __forceinline__ void full_level(const float* __restrict__ simg,
                                           const float* __restrict__ dimg, int H,
                                           int ty, int tx, float pary, float parx, bool first,
                                           float* win, float* st, float* dist, int t,
                                           float& roy, float& rox) {
    float dyf = 0.f, dxf = 0.f;
    if (!first) inherit(H, ty, tx, pary, parx, dyf, dxf);
    const int ioy = (int)dyf, iox = (int)dxf;
    const int y0 = ty * 16 + ioy - 5;
    const int x0 = tx * 16 + iox - 5;

    for (int idx = t; idx < 676; idx += 256) {
        int r = idx / 26, c = idx - r * 26;
        int gy = min(max(y0 + r, 0), H - 1);
        int gx = min(max(x0 + c, 0), H - 1);
        win[r * 28 + c] = dimg[gy * H + gx];
    }
    if (t < 64) {
        int r = t >> 2, q = t & 3;
        const float4* srow = (const float4*)(simg + (size_t)(ty * 16 + r) * H + tx * 16);
        ((float4*)&st[r * 16])[q] = srow[q];
    }
    __syncthreads();   // B1

    const int dy = t >> 4;
    if (dy < 11) {
        float acc[11];
        #pragma unroll
        for (int q = 0; q < 11; ++q) acc[q] = 0.f;
        const int i = t & 15;
        float w[28], s[16];
        const float4* wp = (const float4*)&win[(dy + i) * 28];
        #pragma unroll
        for (int q = 0; q < 7; ++q) ((float4*)w)[q] = wp[q];
        const float4* sp = (const float4*)&st[i * 16];
        #pragma unroll
        for (int q = 0; q < 4; ++q) ((float4*)s)[q] = sp[q];
        #pragma unroll
        for (int dx = 0; dx < 11; ++dx) {
            #pragma unroll
            for (int j = 0; j < 16; ++j) {
                float d = w[dx + j] - s[j];
                acc[dx] = fmaf(d, d, acc[dx]);
            }
        }
        #pragma unroll
        for (int m = 1; m <= 8; m <<= 1) {
            #pragma unroll
            for (int dx = 0; dx < 11; ++dx) acc[dx] += __shfl_xor(acc[dx], m);
        }
        if ((t & 15) == 0) {
            float ay = (float)(dy - 5) * (1.f / 11.f);
            #pragma unroll
            for (int dx = 0; dx < 11; ++dx) {
                float ax = (float)(dx - 5) * (1.f / 11.f);
                dist[dy * 11 + dx] = acc[dx] * (1.f / 256.f) + 0.1f * (ay * ay + ax * ax);
            }
        }
    }
    __syncthreads();   // B2

    float bv; int bk;
    argmin81(dist, t & 63, bv, bk);
    refine(dist, bk, dyf, dxf, roy, rox);
}

// 128-thread half-slot level (R4's FULL=false verbatim), returns min_dist too.
__device__ __forceinline__ void half_level(const float* __restrict__ simg,
                                           const float* __restrict__ dimg, int H,
                                           int ty, int tx, float pary, float parx,
                                           float* win, float* st, float* dist, int lt,
                                           float& roy, float& rox, float& rod) {
    float dyf, dxf;
    inherit(H, ty, tx, pary, parx, dyf, dxf);
    const int ioy = (int)dyf, iox = (int)dxf;
    const int y0 = ty * 16 + ioy - 5;
    const int x0 = tx * 16 + iox - 5;

    for (int idx = lt; idx < 676; idx += 128) {
        int r = idx / 26, c = idx - r * 26;
        int gy = min(max(y0 + r, 0), H - 1);
        int gx = min(max(x0 + c, 0), H - 1);
        win[r * 28 + c] = dimg[gy * H + gx];
    }
    if (lt < 64) {
        int r = lt >> 2, q = lt & 3;
        const float4* srow = (const float4*)(simg + (size_t)(ty * 16 + r) * H + tx * 16);
        ((float4*)&st[r * 16])[q] = srow[q];
    }
    __syncthreads();   // B1

    const int dy = lt >> 3;
    if (dy < 11) {
        float acc[11];
        #pragma unroll
        for (int q = 0; q < 11; ++q) acc[q] = 0.f;
        #pragma unroll
        for (int rr = 0; rr < 2; ++rr) {
            const int i = (lt & 7) * 2 + rr;
            float w[28], s[16];
            const float4* wp = (const float4*)&win[(dy + i) * 28];
            #pragma unroll
            for (int q = 0; q < 7; ++q) ((float4*)w)[q] = wp[q];
            const float4* sp = (const float4*)&st[i * 16];
            #pragma unroll
            for (int q = 0; q < 4; ++q) ((float4*)s)[q] = sp[q];
            #pragma unroll
            for (int dx = 0; dx < 11; ++dx) {
                #pragma unroll
                for (int j = 0; j < 16; ++j) {
                    float d = w[dx + j] - s[j];
                    acc[dx] = fmaf(d, d, acc[dx]);
                }
            }
        }
        #pragma unroll
        for (int m = 1; m <= 4; m <<= 1) {
            #pragma unroll
            for (int dx = 0; dx < 11; ++dx) acc[dx] += __shfl_xor(acc[dx], m);
        }
        if ((lt & 7) == 0) {
            float ay = (float)(dy - 5) * (1.f / 11.f);
            #pragma unroll
            for (int dx = 0; dx < 11; ++dx) {
                float ax = (float)(dx - 5) * (1.f / 11.f);
                dist[dy * 11 + dx] = acc[dx] * (1.f / 256.f) + 0.1f * (ay * ay + ax * ax);
            }
        }
    }
    __syncthreads();   // B2

    float bv; int bk;
    argmin81(dist, lt & 63, bv, bk);
    refine(dist, bk, dyf, dxf, roy, rox);
    rod = bv;
}

// ---------------------------------------------------------------------------
// K2: one block per S1 tile (1024 x 256thr). L3,L2,L1 full rounds; L0 merged
// quad (fast path) or R4 half-rounds (border fallback).
// LDS pool (floats): [0..783] winF / slot0 win ; [784..1039] stF / slot0 st ;
// [1040..1823] slot1 win ; [1824..2079] slot1 st ; quad: win42 [0..1847] s44,
// stQ [1848..2871] 32x32, distQ [2872..3383] 4x128. dist0=2872, dist1=3000 —
// dist regions only written after a barrier that follows all refine reads.
// ---------------------------------------------------------------------------
__global__ void __launch_bounds__(256, 4)
step_chain_kernel(const float* __restrict__ src, const float* __restrict__ dst,
                  const float* __restrict__ ws, float* __restrict__ out) {
    __shared__ float pool[3384];
    float* winF  = pool;
    float* stF   = pool + 784;
    float* winS1 = pool + 1040;
    float* stS1  = pool + 1824;
    float* win42 = pool;           // quad window, 42 rows stride 44
    float* stQ   = pool + 1848;    // quad src 32x32
    float* distQ = pool + 2872;    // 4 x 128
    float* dist0 = pool + 2872;
    float* dist1 = pool + 3000;

    const float* sL1 = ws;
    const float* dL1 = sL1 + 4 * 65536;
    const float* sL2 = dL1 + 4 * 65536;
    const float* dL2 = sL2 + 4 * 16384;
    const float* sL3 = dL2 + 4 * 16384;
    const float* dL3 = sL3 + 4 * 4096;

    const int gid = blockIdx.x;
    const int b   = gid >> 8;
    const int ty1 = (gid >> 4) & 15;
    const int tx1 = gid & 15;
    const int t   = threadIdx.x;

    const float* s0 = src + (size_t)b * 262144; const float* d0 = dst + (size_t)b * 262144;
    const float* s1 = sL1 + (size_t)b * 65536;  const float* d1 = dL1 + (size_t)b * 65536;
    const float* s2 = sL2 + (size_t)b * 16384;  const float* d2 = dL2 + (size_t)b * 16384;
    const float* s3 = sL3 + (size_t)b * 4096;   const float* d3 = dL3 + (size_t)b * 4096;

    float oy, ox;
    full_level(s3, d3,  64, ty1 >> 2, tx1 >> 2, 0.f, 0.f, true,  winF, stF, dist0, t, oy, ox);
    full_level(s2, d2, 128, ty1 >> 1, tx1 >> 1, oy, ox, false, winF, stF, dist0, t, oy, ox);
    full_level(s1, d1, 256, ty1,      tx1,      oy, ox, false, winF, stF, dist0, t, oy, ox);

    // ---- L0: fast quad path iff no child's inherit clamp triggers (uniform). ----
    const float cy = 2.f * oy + (float)(ty1 * 32);
    const float cx = 2.f * ox + (float)(tx1 * 32);
    const bool fastq = (cy >= 0.f) && (cy + 16.f <= 496.f) &&
                       (cx >= 0.f) && (cx + 16.f <= 496.f);

    if (fastq) {
        const float dyf = rintf(2.f * oy), dxf = rintf(2.f * ox);
        const int Y0 = ty1 * 32 + (int)dyf - 5;
        const int X0 = tx1 * 32 + (int)dxf - 5;

        // Stage merged 42x42 window (stride 44, cols 42-43 pad staged too) + 32x32 src.
        for (int idx = t; idx < 1848; idx += 256) {
            int r = idx / 44, c = idx - r * 44;
            int gy = min(max(Y0 + r, 0), 511);
            int gx = min(max(X0 + c, 0), 511);
            win42[idx] = d0[gy * 512 + gx];
        }
        {
            int r = t >> 3, q = t & 7;
            const float4* srow = (const float4*)(s0 + (size_t)(ty1 * 32 + r) * 512 + tx1 * 32);
            ((float4*)&stQ[r * 32])[q] = srow[q];
        }
        __syncthreads();   // B1

        // SSD: 4 child passes, 1 row/lane (16-lane rowgroups), same fp order as full_level.
        const int dy = t >> 4;
        const int i  = t & 15;
        if (dy < 11) {
            #pragma unroll
            for (int c = 0; c < 4; ++c) {
                const int rb = (c >> 1) * 16, cb = (c & 1) * 16;
                float acc[11];
                #pragma unroll
                for (int q = 0; q < 11; ++q) acc[q] = 0.f;
                float w[28], s[16];
                const float4* wp = (const float4*)&win42[(rb + dy + i) * 44 + cb];
                #pragma unroll
                for (int q = 0; q < 7; ++q) ((float4*)w)[q] = wp[q];
                const float4* sp = (const float4*)&stQ[(rb + i) * 32 + cb];
                #pragma unroll
                for (int q = 0; q < 4; ++q) ((float4*)s)[q] = sp[q];
                #pragma unroll
                for (int dx = 0; dx < 11; ++dx) {
                    #pragma unroll
                    for (int j = 0; j < 16; ++j) {
                        float d = w[dx + j] - s[j];
                        acc[dx] = fmaf(d, d, acc[dx]);
                    }
                }
                #pragma unroll
                for (int m = 1; m <= 8; m <<= 1) {
                    #pragma unroll
                    for (int dx = 0; dx < 11; ++dx) acc[dx] += __shfl_xor(acc[dx], m);
                }
                if (i == 0) {
                    float ay = (float)(dy - 5) * (1.f / 11.f);
                    #pragma unroll
                    for (int dx = 0; dx < 11; ++dx) {
                        float ax = (float)(dx - 5) * (1.f / 11.f);
                        distQ[c * 128 + dy * 11 + dx] = acc[dx] * (1.f / 256.f) + 0.1f * (ay * ay + ax * ax);
                    }
                }
            }
        }
        __syncthreads();   // B2

        // Wave w: argmin + refine + expand for child w.
        const int w    = t >> 6;
        const int lane = t & 63;
        const float* dc = &distQ[w * 128];
        float bv; int bk;
        argmin81(dc, lane, bv, bk);
        float coy, cox;
        refine(dc, bk, dyf, dxf, coy, cox);

        const int ty0 = 2 * ty1 + (w >> 1), tx0 = 2 * tx1 + (w & 1);
        int r = lane >> 2, c = (lane & 3) * 4;
        size_t pi = ((size_t)(b * 512 + ty0 * 16 + r)) * 512 + tx0 * 16 + c;
        float4 o2; o2.x = coy; o2.y = cox; o2.z = coy; o2.w = cox;
        float4* po = (float4*)(out + 2 * pi);
        po[0] = o2; po[1] = o2;
        float4 dd; dd.x = bv; dd.y = bv; dd.z = bv; dd.w = bv;
        *(float4*)(out + (size_t)NPIX * 2 + pi) = dd;
    } else {
        // ---- fallback: R4's two half-rounds (slot = wave pair). ----
        const int slot = t >> 7;
        const int s_t  = t & 127;
        float* win  = slot ? winS1 : winF;
        float* st   = slot ? stS1  : stF;
        float* dist = slot ? dist1 : dist0;

        #pragma unroll
        for (int half = 0; half < 2; ++half) {
            const int ty0 = 2 * ty1 + half, tx0 = 2 * tx1 + slot;
            float coy, cox, od;
            half_level(s0, d0, 512, ty0, tx0, oy, ox, win, st, dist, s_t, coy, cox, od);
            int r = s_t >> 3, c = (s_t & 7) * 2;
            size_t pi = ((size_t)(b * 512 + ty0 * 16 + r)) * 512 + tx0 * 16 + c;
            float2 o; o.x = coy; o.y = cox;
            ((float2*)out)[pi]     = o;
            ((float2*)out)[pi + 1] = o;
            float2 dd; dd.x = od; dd.y = od;
            *(float2*)(out + (size_t)NPIX * 2 + pi) = dd;
        }
    }
}

extern "C" void kernel_launch(void* const* d_in, const int* in_sizes, int n_in,
                              void* d_out, int out_size, void* d_ws, size_t ws_size,
                              hipStream_t stream) {
    const float* src = (const float*)d_in[0];   // (4,1,512,512)
    const float* dst = (const float*)d_in[1];   // (4,1,512,512)
    float* out = (float*)d_out;                  // offsets (NPIX*2) ++ dist (NPIX)
    float* ws  = (float*)d_ws;                   // pyramid levels, 2.75 MB

    hipLaunchKernelGGL(pyramid_kernel, dim3(16, 16, 8), dim3(256), 0, stream, src, dst, ws);
    hipLaunchKernelGGL(step_chain_kernel, dim3(1024), dim3(256), 0, stream, src, dst, ws, out);
}